// Round 2
// baseline (6659.411 us; speedup 1.0000x reference)
//
#include <hip/hip_runtime.h>
#include <stdint.h>

// ---------------- problem constants ----------------
#define NLAYER 13
#define DMODEL 512
#define SEQ    65
#define BATCH  128
#define MROWS  (BATCH*SEQ)   // 8320 = 65 * 128 exactly
#define NHEAD  8
#define DFFH   1920          // half of 2*DFF
#define MTILES 65            // MROWS / 128
#define MBAND  9             // ceil(65/8) m-tiles per XCD slice

typedef __bf16 bf16x8 __attribute__((ext_vector_type(8)));
typedef float  f32x4  __attribute__((ext_vector_type(4)));

__device__ __forceinline__ float bf2f(unsigned short u) {
    union { unsigned int i; float f; } c; c.i = ((unsigned int)u) << 16; return c.f;
}
__device__ __forceinline__ unsigned short f2bf(float f) {
    union { float f; unsigned int i; } c; c.f = f;
    unsigned int u = c.i;
    u += 0x7fffu + ((u >> 16) & 1u);   // RNE
    return (unsigned short)(u >> 16);
}
__device__ __forceinline__ float gelu_exact(float x) {
    return 0.5f * x * (1.0f + erff(x * 0.70710678118654752f));
}

// ---------------- weight convert + transpose to bf16 ----------------
__global__ __launch_bounds__(256) void transpose_f32_bf16(
    const float* __restrict__ src, unsigned short* __restrict__ dst,
    int R, int C, int Cpad, long srcLS, long dstLS, int rowOff)
{
    __shared__ float tile[32][33];
    int l  = blockIdx.z;
    int c0 = blockIdx.x * 32, r0 = blockIdx.y * 32;
    const float* s = src + (long)l * srcLS;
    unsigned short* d = dst + (long)l * dstLS;
    int tx = threadIdx.x, ty = threadIdx.y;
#pragma unroll
    for (int k = 0; k < 4; k++) {
        int r = r0 + ty + 8*k, c = c0 + tx;
        float v = (r < R && c < C) ? s[(long)r * C + c] : 0.0f;
        tile[ty + 8*k][tx] = v;
    }
    __syncthreads();
#pragma unroll
    for (int k = 0; k < 4; k++) {
        int c = c0 + ty + 8*k, r = r0 + tx;
        if (c < Cpad && r < R)
            d[(long)(rowOff + c) * R + r] = f2bf(tile[tx][ty + 8*k]);
    }
}

// ---------------- stack bq|bk|bv -> (L,1536) ----------------
__global__ __launch_bounds__(256) void stack_bias_kernel(
    const float* __restrict__ bq, const float* __restrict__ bk,
    const float* __restrict__ bv, float* __restrict__ bqkv)
{
    int idx = blockIdx.x * 256 + threadIdx.x;
    if (idx >= NLAYER * 1536) return;
    int l = idx / 1536, r = idx - l * 1536;
    float v;
    if (r < 512)       v = bq[l*512 + r];
    else if (r < 1024) v = bk[l*512 + r - 512];
    else               v = bv[l*512 + r - 1024];
    bqkv[idx] = v;
}

// ---------------- embedding ----------------
__global__ __launch_bounds__(256) void embed_kernel(
    const float* __restrict__ x, const float* __restrict__ conv_w,
    const float* __restrict__ conv_b, const float* __restrict__ cls_tok,
    const float* __restrict__ abs_pos, const float* __restrict__ file_emb,
    const float* __restrict__ rank_emb, const float* __restrict__ diag_emb,
    const float* __restrict__ adiag_emb, float* __restrict__ h)
{
    int b = blockIdx.y, sg = blockIdx.x, t = threadIdx.x;
    if (sg == 8) {
        for (int d = t; d < 512; d += 256)
            h[(long)b * SEQ * 512 + d] = cls_tok[d];
        return;
    }
    __shared__ float xs[112][8];
    for (int idx = t; idx < 112*8; idx += 256) {
        int c = idx >> 3, j = idx & 7;
        xs[c][j] = x[((long)b*112 + c)*64 + sg*8 + j];
    }
    __syncthreads();
    int d0 = t, d1 = t + 256;
    float acc0[8] = {}, acc1[8] = {};
    for (int c = 0; c < 112; c++) {
        float w0 = conv_w[c*512 + d0], w1 = conv_w[c*512 + d1];
#pragma unroll
        for (int j = 0; j < 8; j++) { acc0[j] += xs[c][j]*w0; acc1[j] += xs[c][j]*w1; }
    }
#pragma unroll
    for (int j = 0; j < 8; j++) {
        int sq = sg*8 + j, r = sq >> 3, f = sq & 7;
        long row = ((long)b * SEQ + 1 + sq) * 512;
        h[row + d0] = acc0[j] + conv_b[d0] + abs_pos[sq*512+d0] + file_emb[f*512+d0]
                    + rank_emb[r*512+d0] + diag_emb[(r+f)*512+d0] + adiag_emb[(r-f+7)*512+d0];
        h[row + d1] = acc1[j] + conv_b[d1] + abs_pos[sq*512+d1] + file_emb[f*512+d1]
                    + rank_emb[r*512+d1] + diag_emb[(r+f)*512+d1] + adiag_emb[(r-f+7)*512+d1];
    }
}

// ---------------- LayerNorm fp32 -> bf16 (wave per row) ----------------
__global__ __launch_bounds__(256) void ln_kernel(
    const float* __restrict__ hx, const float* __restrict__ g,
    const float* __restrict__ bb, unsigned short* __restrict__ o)
{
    int row  = blockIdx.x * 4 + (threadIdx.x >> 6);
    int lane = threadIdx.x & 63;
    const float4* xr = (const float4*)(hx + (long)row * 512);
    float4 v0 = xr[lane], v1 = xr[lane + 64];
    float s  = v0.x+v0.y+v0.z+v0.w + v1.x+v1.y+v1.z+v1.w;
    float s2 = v0.x*v0.x+v0.y*v0.y+v0.z*v0.z+v0.w*v0.w
             + v1.x*v1.x+v1.y*v1.y+v1.z*v1.z+v1.w*v1.w;
    for (int off = 32; off; off >>= 1) { s += __shfl_xor(s, off); s2 += __shfl_xor(s2, off); }
    float mean = s * (1.0f/512.0f);
    float var  = s2 * (1.0f/512.0f) - mean*mean;
    float rs   = rsqrtf(var + 1e-5f);
    const float4* gr = (const float4*)g; const float4* br = (const float4*)bb;
    float4 g0 = gr[lane], g1 = gr[lane+64], b0 = br[lane], b1 = br[lane+64];
    ushort4 o0, o1;
    o0.x = f2bf((v0.x-mean)*rs*g0.x + b0.x);
    o0.y = f2bf((v0.y-mean)*rs*g0.y + b0.y);
    o0.z = f2bf((v0.z-mean)*rs*g0.z + b0.z);
    o0.w = f2bf((v0.w-mean)*rs*g0.w + b0.w);
    o1.x = f2bf((v1.x-mean)*rs*g1.x + b1.x);
    o1.y = f2bf((v1.y-mean)*rs*g1.y + b1.y);
    o1.z = f2bf((v1.z-mean)*rs*g1.z + b1.z);
    o1.w = f2bf((v1.w-mean)*rs*g1.w + b1.w);
    ushort4* orow = (ushort4*)(o + (long)row * 512);
    orow[lane] = o0; orow[lane + 64] = o1;
}

// ---------------- MFMA GEMM: XCD-swizzled, BK=64, swizzled LDS -----------
// tile 128x128, BK=64, 4 waves (32 rows x 128 cols each), 16x16x32 MFMA.
// 1D grid of 72*nT blocks: xcd = id&7 owns a contiguous band of 9 m-tiles.
// K-loop: reg-prefetch pipeline (R0-proven replay-safe — no counted vmcnt,
// no gl2lds double-buffer): tile t+1's global loads issue into VGPRs while
// tile t computes; ds_write at top of next iteration. BK=64 halves the
// number of barrier envelopes vs BK=32 (m233: 2-phase critical path is
// stage+drain+barrier, so fewer envelopes per K = less stall).
// LDS XOR-swizzle (T2, both-sides involution): elem k of row r lives at
// r*64 + (k ^ ((r&7)*8)). At BK=64 the row stride is 128B, which
// un-swizzled is a 16-way read conflict; swizzled, each 16-lane quad-group
// spreads over 8 bank slots -> 2-way -> free.
// MODE 0: bias, bf16 out   MODE 1: bias + fp32 residual, fp32 out
// MODE 2: GLU pair -> bf16 gelu(u1)*u2, out (M,1920)
// MODE 3: policy masked store -> fp32 (B,4608)
template<int MODE>
__global__ __launch_bounds__(256) void gemm128(
    const unsigned short* __restrict__ A, const unsigned short* __restrict__ Bt,
    const float* __restrict__ bias, const float* __restrict__ res,
    void* __restrict__ out, int K, int ldo, int nT)
{
    __shared__ __attribute__((aligned(16))) unsigned short As[128*64];
    __shared__ __attribute__((aligned(16))) unsigned short Bs[128*64];
    int id = blockIdx.x;
    int xcd = id & 7, jj = id >> 3;
    int bn  = jj % nT;
    int mt  = xcd * MBAND + jj / nT;
    if (mt >= MTILES) return;
    int m0 = mt * 128;
    int tid = threadIdx.x;
    int lane = tid & 63, w = tid >> 6;
    int quad = lane >> 4, col = lane & 15;

    // ---- staging map: 4 rounds x (256 threads x 8 bf16) per operand ----
    // round r: row = r*32 + tid/8, k-elems [ (tid&7)*8, +8 )
    int rb  = tid >> 3;          // 0..31 row-within-round
    int kel = (tid & 7) * 8;     // k element offset (8 bf16 = 16B)
    // swizzled LDS write dest (elems); involution swz = (row&7)*8
    int wBase = rb * 64 + (kel ^ ((rb & 7) * 8));   // += r*2048 per round

    const unsigned short* Ar[4];
    const unsigned short* Br[4];
#pragma unroll
    for (int r = 0; r < 4; r++) {
        int row = r*32 + rb;
        Ar[r] = A + (long)(m0 + row) * K + kel;
        int br;
        if (MODE == 2) br = (row < 64) ? (bn*64 + row) : (1920 + bn*64 + row - 64);
        else           br = bn*128 + row;
        Br[r] = Bt + (long)br * K + kel;
    }

    f32x4 acc[2][8] = {};
    int swz = (col & 7) * 8;     // read-side involution (row&7 == col&7)

    int4 pa[4], pb[4];
#pragma unroll
    for (int r = 0; r < 4; r++) { pa[r] = *(const int4*)(Ar[r]); pb[r] = *(const int4*)(Br[r]); }

    for (int k0 = 0; k0 < K; k0 += 64) {
        __syncthreads();   // prior iteration's frag reads done
#pragma unroll
        for (int r = 0; r < 4; r++) {
            *(int4*)&As[wBase + r*2048] = pa[r];
            *(int4*)&Bs[wBase + r*2048] = pb[r];
        }
        __syncthreads();
        int kn = k0 + 64;
        if (kn < K) {   // prefetch next tile into VGPRs while computing
#pragma unroll
            for (int r = 0; r < 4; r++) {
                pa[r] = *(const int4*)(Ar[r] + kn);
                pb[r] = *(const int4*)(Br[r] + kn);
            }
        }
#pragma unroll
        for (int kk = 0; kk < 2; kk++) {
            bf16x8 af[2], bfr[8];
#pragma unroll
            for (int i = 0; i < 2; i++)
                af[i] = *(const bf16x8*)(&As[(w*32 + i*16 + col)*64 + ((quad*8 + kk*32) ^ swz)]);
#pragma unroll
            for (int t = 0; t < 8; t++)
                bfr[t] = *(const bf16x8*)(&Bs[(t*16 + col)*64 + ((quad*8 + kk*32) ^ swz)]);
#pragma unroll
            for (int i = 0; i < 2; i++)
#pragma unroll
                for (int t = 0; t < 8; t++)
                    acc[i][t] = __builtin_amdgcn_mfma_f32_16x16x32_bf16(af[i], bfr[t], acc[i][t], 0, 0, 0);
        }
    }

    // ---- epilogue ----  C/D layout: col = lane&15, row = quad*4 + reg
    if (MODE == 2) {
        unsigned short* O = (unsigned short*)out;
        int gn0 = bn * 64;
#pragma unroll
        for (int i = 0; i < 2; i++)
#pragma unroll
        for (int t = 0; t < 4; t++) {
            int c = t*16 + col;
            float b1v = bias[gn0 + c];
            float b2v = bias[1920 + gn0 + c];
#pragma unroll
            for (int r = 0; r < 4; r++) {
                int m = m0 + w*32 + i*16 + quad*4 + r;
                float u1 = acc[i][t][r]   + b1v;
                float u2 = acc[i][t+4][r] + b2v;
                O[(long)m * DFFH + gn0 + c] = f2bf(gelu_exact(u1) * u2);
            }
        }
        return;
    }
    int n0 = bn * 128;
#pragma unroll
    for (int i = 0; i < 2; i++)
#pragma unroll
    for (int t = 0; t < 8; t++) {
        int cg = n0 + t*16 + col;
        float bv = (MODE == 3) ? (cg < 72 ? bias[cg] : 0.0f) : bias[cg];
#pragma unroll
        for (int r = 0; r < 4; r++) {
            int m = m0 + w*32 + i*16 + quad*4 + r;
            float v = acc[i][t][r] + bv;
            if (MODE == 0) {
                ((unsigned short*)out)[(long)m * ldo + cg] = f2bf(v);
            } else if (MODE == 1) {
                ((float*)out)[(long)m * ldo + cg] = res[(long)m * ldo + cg] + v;
            } else { // MODE 3 policy
                if (cg < 72) {
                    int b2 = m / 65, s = m - b2 * 65;
                    if (s > 0)
                        ((float*)out)[(long)b2 * 4608 + (s - 1) * 72 + cg] = v;
                }
            }
        }
    }
}

// ---------------- MFMA attention: one block per (head, batch) ----------------
__global__ __launch_bounds__(256) void attn_mfma_kernel(
    const unsigned short* __restrict__ qkv,   // (M,1536) bf16: q|k|v
    const float* __restrict__ rel_bias,       // (13,15,15,8)
    unsigned short* __restrict__ ctx,         // (M,512) bf16
    int layer)
{
    constexpr int QS = 72;
    constexpr int VS = 104;
    constexpr int SS = 68;
    constexpr int PS = 104;
    __shared__ __attribute__((aligned(16))) unsigned short Qs[80*QS];
    __shared__ __attribute__((aligned(16))) unsigned short Ks[80*QS];
    __shared__ __attribute__((aligned(16))) unsigned short Vt[64*VS];
    __shared__ __attribute__((aligned(16))) float Sf[65*SS];
    __shared__ __attribute__((aligned(16))) unsigned short Pb[80*PS];
    __shared__ float bias_s[225];

    int h = blockIdx.x, b = blockIdx.y, t = threadIdx.x;
    int lane = t & 63, w = t >> 6;
    int quad = lane >> 4, col = lane & 15;

    for (int i = t; i < 225; i += 256)
        bias_s[i] = rel_bias[((long)layer*225 + i)*8 + h];

    for (int i = t; i < 65*8; i += 256) {
        int s = i >> 3, c8 = (i & 7) * 8;
        const unsigned short* row = qkv + ((long)(b*65+s))*1536 + h*64 + c8;
        int4 qv = *(const int4*)(row);
        int4 kv = *(const int4*)(row + 512);
        int4 vv = *(const int4*)(row + 1024);
        unsigned short qsc[8];
        const unsigned short* qp = (const unsigned short*)&qv;
#pragma unroll
        for (int j = 0; j < 8; j++) qsc[j] = f2bf(bf2f(qp[j]) * 0.125f);
        *(int4*)&Qs[s*QS + c8] = *(const int4*)qsc;
        *(int4*)&Ks[s*QS + c8] = kv;
        const unsigned short* vp = (const unsigned short*)&vv;
#pragma unroll
        for (int j = 0; j < 8; j++) Vt[(c8+j)*VS + s] = vp[j];
    }
    for (int i = t; i < 64*31; i += 256) {
        int d = i / 31, s = 65 + i % 31;
        Vt[d*VS + s] = 0;
    }
    __syncthreads();

    for (int tt = w; tt < 25; tt += 4) {
        int mi = tt / 5, nj = tt % 5;
        f32x4 acc = {};
        bf16x8 a0 = *(const bf16x8*)&Qs[(mi*16+col)*QS + quad*8];
        bf16x8 b0 = *(const bf16x8*)&Ks[(nj*16+col)*QS + quad*8];
        acc = __builtin_amdgcn_mfma_f32_16x16x32_bf16(a0, b0, acc, 0, 0, 0);
        bf16x8 a1 = *(const bf16x8*)&Qs[(mi*16+col)*QS + 32 + quad*8];
        bf16x8 b1 = *(const bf16x8*)&Ks[(nj*16+col)*QS + 32 + quad*8];
        acc = __builtin_amdgcn_mfma_f32_16x16x32_bf16(a1, b1, acc, 0, 0, 0);
#pragma unroll
        for (int r = 0; r < 4; r++) {
            int qi = mi*16 + quad*4 + r, kj = nj*16 + col;
            if (qi < 65 && kj < 65) {
                float v = acc[r];
                if (qi >= 1 && kj >= 1) {
                    int i2 = qi - 1, j2 = kj - 1;
                    int dr = (i2 >> 3) - (j2 >> 3) + 7;
                    int df = (i2 & 7) - (j2 & 7) + 7;
                    v += bias_s[dr*15 + df];
                }
                Sf[qi*SS + kj] = v;
            }
        }
    }
    __syncthreads();

    for (int r = w; r < 65; r += 4) {
        float x0 = Sf[r*SS + lane];
        float x1 = (lane == 0) ? Sf[r*SS + 64] : -1e30f;
        float mx = fmaxf(x0, x1);
        for (int off = 32; off; off >>= 1) mx = fmaxf(mx, __shfl_xor(mx, off));
        float e0 = __expf(x0 - mx);
        float e1 = (lane == 0) ? __expf(x1 - mx) : 0.0f;
        float sm = e0 + e1;
        for (int off = 32; off; off >>= 1) sm += __shfl_xor(sm, off);
        float inv = 1.0f / sm;
        Pb[r*PS + lane] = f2bf(e0 * inv);
        if (lane == 0)  Pb[r*PS + 64] = f2bf(e1 * inv);
        if (lane >= 1 && lane <= 31) Pb[r*PS + 64 + lane] = 0;
    }
    __syncthreads();

    for (int tt = w; tt < 20; tt += 4) {
        int mi = tt >> 2, dj = tt & 3;
        f32x4 acc = {};
#pragma unroll
        for (int ks = 0; ks < 3; ks++) {
            bf16x8 a  = *(const bf16x8*)&Pb[(mi*16+col)*PS + ks*32 + quad*8];
            bf16x8 bb = *(const bf16x8*)&Vt[(dj*16+col)*VS + ks*32 + quad*8];
            acc = __builtin_amdgcn_mfma_f32_16x16x32_bf16(a, bb, acc, 0, 0, 0);
        }
#pragma unroll
        for (int r = 0; r < 4; r++) {
            int qi = mi*16 + quad*4 + r;
            if (qi < 65)
                ctx[((long)(b*65+qi))*512 + h*64 + dj*16 + col] = f2bf(acc[r]);
        }
    }
}

// ---------------- value head ----------------
__global__ __launch_bounds__(256) void value_head_kernel(
    const unsigned short* __restrict__ hn,
    const float* __restrict__ vw1, const float* __restrict__ vb1,
    const float* __restrict__ vw2, const float* __restrict__ vb2,
    const float* __restrict__ vw3, const float* __restrict__ vb3,
    float* __restrict__ outv)
{
    int b = blockIdx.x, t = threadIdx.x;
    __shared__ float cls[512], v1[256], v2[128];
    for (int d = t; d < 512; d += 256) cls[d] = bf2f(hn[(long)b * SEQ * 512 + d]);
    __syncthreads();
    {
        float a = vb1[t];
        for (int c = 0; c < 512; c++) a += cls[c] * vw1[c*256 + t];
        v1[t] = gelu_exact(a);
    }
    __syncthreads();
    if (t < 128) {
        float a = vb2[t];
        for (int c = 0; c < 256; c++) a += v1[c] * vw2[c*128 + t];
        v2[t] = gelu_exact(a);
    }
    __syncthreads();
    if (t < 3) {
        float a = vb3[t];
        for (int c = 0; c < 128; c++) a += v2[c] * vw3[c*3 + t];
        outv[b*3 + t] = a;
    }
}

// ---------------- host orchestration ----------------
extern "C" void kernel_launch(void* const* d_in, const int* in_sizes, int n_in,
                              void* d_out, int out_size, void* d_ws, size_t ws_size,
                              hipStream_t stream)
{
    (void)in_sizes; (void)n_in; (void)out_size; (void)ws_size;
    const float* x        = (const float*)d_in[0];
    const float* conv_w   = (const float*)d_in[1];
    const float* conv_b   = (const float*)d_in[2];
    const float* cls_tok  = (const float*)d_in[3];
    const float* abs_pos  = (const float*)d_in[4];
    const float* file_emb = (const float*)d_in[5];
    const float* rank_emb = (const float*)d_in[6];
    const float* diag_emb = (const float*)d_in[7];
    const float* adiag    = (const float*)d_in[8];
    const float* ln1_g    = (const float*)d_in[9];
    const float* ln1_b    = (const float*)d_in[10];
    const float* wq       = (const float*)d_in[11];
    const float* bq       = (const float*)d_in[12];
    const float* wk       = (const float*)d_in[13];
    const float* bk       = (const float*)d_in[14];
    const float* wv       = (const float*)d_in[15];
    const float* bv       = (const float*)d_in[16];
    const float* wo       = (const float*)d_in[17];
    const float* bo       = (const float*)d_in[18];
    const float* rel_bias = (const float*)d_in[19];
    const float* ln2_g    = (const float*)d_in[20];
    const float* ln2_b    = (const float*)d_in[21];
    const float* w_ff1    = (const float*)d_in[22];
    const float* b_ff1    = (const float*)d_in[23];
    const float* w_ff2    = (const float*)d_in[24];
    const float* b_ff2    = (const float*)d_in[25];
    const float* out_g    = (const float*)d_in[26];
    const float* out_b    = (const float*)d_in[27];
    const float* vw1      = (const float*)d_in[28];
    const float* vb1      = (const float*)d_in[29];
    const float* vw2      = (const float*)d_in[30];
    const float* vb2      = (const float*)d_in[31];
    const float* vw3      = (const float*)d_in[32];
    const float* vb3      = (const float*)d_in[33];
    const float* pw       = (const float*)d_in[34];
    const float* pb       = (const float*)d_in[35];

    char* p = (char*)d_ws;
    auto alloc = [&](size_t bytes) { void* r = (void*)p; p += (bytes + 255) & ~(size_t)255; return r; };
    unsigned short* qkvT = (unsigned short*)alloc((size_t)NLAYER*1536*512*2);
    unsigned short* woT  = (unsigned short*)alloc((size_t)NLAYER*512*512*2);
    unsigned short* w1T  = (unsigned short*)alloc((size_t)NLAYER*3840*512*2);
    unsigned short* w2T  = (unsigned short*)alloc((size_t)NLAYER*512*1920*2);
    unsigned short* pwT  = (unsigned short*)alloc((size_t)128*512*2);
    float*          bqkv = (float*)alloc((size_t)NLAYER*1536*4);
    float*          h    = (float*)alloc((size_t)MROWS*512*4);
    unsigned short* nbf  = (unsigned short*)alloc((size_t)MROWS*512*2);
    unsigned short* qkvb = (unsigned short*)alloc((size_t)MROWS*1536*2);
    unsigned short* ctxb = (unsigned short*)alloc((size_t)MROWS*512*2);
    unsigned short* gbuf = (unsigned short*)alloc((size_t)MROWS*1920*2);

    dim3 tb(32, 8);
    transpose_f32_bf16<<<dim3(16,16,NLAYER), tb, 0, stream>>>(wq, qkvT, 512, 512, 512, 512L*512, 1536L*512, 0);
    transpose_f32_bf16<<<dim3(16,16,NLAYER), tb, 0, stream>>>(wk, qkvT, 512, 512, 512, 512L*512, 1536L*512, 512);
    transpose_f32_bf16<<<dim3(16,16,NLAYER), tb, 0, stream>>>(wv, qkvT, 512, 512, 512, 512L*512, 1536L*512, 1024);
    transpose_f32_bf16<<<dim3(16,16,NLAYER), tb, 0, stream>>>(wo, woT, 512, 512, 512, 512L*512, 512L*512, 0);
    transpose_f32_bf16<<<dim3(120,16,NLAYER), tb, 0, stream>>>(w_ff1, w1T, 512, 3840, 3840, 512L*3840, 3840L*512, 0);
    transpose_f32_bf16<<<dim3(16,60,NLAYER), tb, 0, stream>>>(w_ff2, w2T, 1920, 512, 512, 1920L*512, 512L*1920, 0);
    transpose_f32_bf16<<<dim3(4,16,1), tb, 0, stream>>>(pw, pwT, 512, 72, 128, 0, 0, 0);
    stack_bias_kernel<<<(NLAYER*1536 + 255)/256, 256, 0, stream>>>(bq, bk, bv, bqkv);

    embed_kernel<<<dim3(9, BATCH), 256, 0, stream>>>(x, conv_w, conv_b, cls_tok, abs_pos,
                                                     file_emb, rank_emb, diag_emb, adiag, h);

    for (int l = 0; l < NLAYER; l++) {
        ln_kernel<<<MROWS/4, 256, 0, stream>>>(h, ln1_g + l*512, ln1_b + l*512, nbf);
        gemm128<0><<<72*12, 256, 0, stream>>>(nbf, qkvT + (size_t)l*1536*512,
                                              bqkv + l*1536, nullptr, qkvb, 512, 1536, 12);
        attn_mfma_kernel<<<dim3(NHEAD, BATCH), 256, 0, stream>>>(qkvb, rel_bias, ctxb, l);
        gemm128<1><<<72*4, 256, 0, stream>>>(ctxb, woT + (size_t)l*512*512,
                                             bo + l*512, h, h, 512, 512, 4);
        ln_kernel<<<MROWS/4, 256, 0, stream>>>(h, ln2_g + l*512, ln2_b + l*512, nbf);
        gemm128<2><<<72*30, 256, 0, stream>>>(nbf, w1T + (size_t)l*3840*512,
                                              b_ff1 + l*3840, nullptr, gbuf, 512, 0, 30);
        gemm128<1><<<72*4, 256, 0, stream>>>(gbuf, w2T + (size_t)l*512*1920,
                                             b_ff2 + l*512, h, h, 1920, 512, 4);
    }

    ln_kernel<<<MROWS/4, 256, 0, stream>>>(h, out_g, out_b, nbf);
    gemm128<3><<<72*1, 256, 0, stream>>>(nbf, pwT, pb, nullptr, (float*)d_out, 512, 0, 1);
    value_head_kernel<<<BATCH, 256, 0, stream>>>(nbf, vw1, vb1, vw2, vb2, vw3, vb3,
                                                 (float*)d_out + (size_t)BATCH*4608);
}

// Round 3
// 2917.971 us; speedup vs baseline: 2.2822x; 2.2822x over previous
//
#include <hip/hip_runtime.h>
#include <stdint.h>

// ---------------- problem constants ----------------
#define NLAYER 13
#define DMODEL 512
#define SEQ    65
#define BATCH  128
#define MROWS  (BATCH*SEQ)   // 8320 = 65 * 128 exactly
#define NHEAD  8
#define DFFH   1920          // half of 2*DFF
#define MTILES 65            // MROWS / 128
#define MBAND  9             // ceil(65/8) m-tiles per XCD slice
#define LDK    40            // LDS row stride in elems (80 B = 20 banks, odd*4 -> 2-way)

typedef __bf16 bf16x8 __attribute__((ext_vector_type(8)));
typedef float  f32x4  __attribute__((ext_vector_type(4)));

__device__ __forceinline__ float bf2f(unsigned short u) {
    union { unsigned int i; float f; } c; c.i = ((unsigned int)u) << 16; return c.f;
}
__device__ __forceinline__ unsigned short f2bf(float f) {
    union { float f; unsigned int i; } c; c.f = f;
    unsigned int u = c.i;
    u += 0x7fffu + ((u >> 16) & 1u);   // RNE
    return (unsigned short)(u >> 16);
}
__device__ __forceinline__ float gelu_exact(float x) {
    return 0.5f * x * (1.0f + erff(x * 0.70710678118654752f));
}

// ---------------- weight convert + transpose to bf16 ----------------
__global__ __launch_bounds__(256) void transpose_f32_bf16(
    const float* __restrict__ src, unsigned short* __restrict__ dst,
    int R, int C, int Cpad, long srcLS, long dstLS, int rowOff)
{
    __shared__ float tile[32][33];
    int l  = blockIdx.z;
    int c0 = blockIdx.x * 32, r0 = blockIdx.y * 32;
    const float* s = src + (long)l * srcLS;
    unsigned short* d = dst + (long)l * dstLS;
    int tx = threadIdx.x, ty = threadIdx.y;
#pragma unroll
    for (int k = 0; k < 4; k++) {
        int r = r0 + ty + 8*k, c = c0 + tx;
        float v = (r < R && c < C) ? s[(long)r * C + c] : 0.0f;
        tile[ty + 8*k][tx] = v;
    }
    __syncthreads();
#pragma unroll
    for (int k = 0; k < 4; k++) {
        int c = c0 + ty + 8*k, r = r0 + tx;
        if (c < Cpad && r < R)
            d[(long)(rowOff + c) * R + r] = f2bf(tile[tx][ty + 8*k]);
    }
}

// ---------------- stack bq|bk|bv -> (L,1536) ----------------
__global__ __launch_bounds__(256) void stack_bias_kernel(
    const float* __restrict__ bq, const float* __restrict__ bk,
    const float* __restrict__ bv, float* __restrict__ bqkv)
{
    int idx = blockIdx.x * 256 + threadIdx.x;
    if (idx >= NLAYER * 1536) return;
    int l = idx / 1536, r = idx - l * 1536;
    float v;
    if (r < 512)       v = bq[l*512 + r];
    else if (r < 1024) v = bk[l*512 + r - 512];
    else               v = bv[l*512 + r - 1024];
    bqkv[idx] = v;
}

// ---------------- embedding ----------------
__global__ __launch_bounds__(256) void embed_kernel(
    const float* __restrict__ x, const float* __restrict__ conv_w,
    const float* __restrict__ conv_b, const float* __restrict__ cls_tok,
    const float* __restrict__ abs_pos, const float* __restrict__ file_emb,
    const float* __restrict__ rank_emb, const float* __restrict__ diag_emb,
    const float* __restrict__ adiag_emb, float* __restrict__ h)
{
    int b = blockIdx.y, sg = blockIdx.x, t = threadIdx.x;
    if (sg == 8) {
        for (int d = t; d < 512; d += 256)
            h[(long)b * SEQ * 512 + d] = cls_tok[d];
        return;
    }
    __shared__ float xs[112][8];
    for (int idx = t; idx < 112*8; idx += 256) {
        int c = idx >> 3, j = idx & 7;
        xs[c][j] = x[((long)b*112 + c)*64 + sg*8 + j];
    }
    __syncthreads();
    int d0 = t, d1 = t + 256;
    float acc0[8] = {}, acc1[8] = {};
    for (int c = 0; c < 112; c++) {
        float w0 = conv_w[c*512 + d0], w1 = conv_w[c*512 + d1];
#pragma unroll
        for (int j = 0; j < 8; j++) { acc0[j] += xs[c][j]*w0; acc1[j] += xs[c][j]*w1; }
    }
#pragma unroll
    for (int j = 0; j < 8; j++) {
        int sq = sg*8 + j, r = sq >> 3, f = sq & 7;
        long row = ((long)b * SEQ + 1 + sq) * 512;
        h[row + d0] = acc0[j] + conv_b[d0] + abs_pos[sq*512+d0] + file_emb[f*512+d0]
                    + rank_emb[r*512+d0] + diag_emb[(r+f)*512+d0] + adiag_emb[(r-f+7)*512+d0];
        h[row + d1] = acc1[j] + conv_b[d1] + abs_pos[sq*512+d1] + file_emb[f*512+d1]
                    + rank_emb[r*512+d1] + diag_emb[(r+f)*512+d1] + adiag_emb[(r-f+7)*512+d1];
    }
}

// ---------------- LayerNorm fp32 -> bf16 (wave per row) ----------------
__global__ __launch_bounds__(256) void ln_kernel(
    const float* __restrict__ hx, const float* __restrict__ g,
    const float* __restrict__ bb, unsigned short* __restrict__ o)
{
    int row  = blockIdx.x * 4 + (threadIdx.x >> 6);
    int lane = threadIdx.x & 63;
    const float4* xr = (const float4*)(hx + (long)row * 512);
    float4 v0 = xr[lane], v1 = xr[lane + 64];
    float s  = v0.x+v0.y+v0.z+v0.w + v1.x+v1.y+v1.z+v1.w;
    float s2 = v0.x*v0.x+v0.y*v0.y+v0.z*v0.z+v0.w*v0.w
             + v1.x*v1.x+v1.y*v1.y+v1.z*v1.z+v1.w*v1.w;
    for (int off = 32; off; off >>= 1) { s += __shfl_xor(s, off); s2 += __shfl_xor(s2, off); }
    float mean = s * (1.0f/512.0f);
    float var  = s2 * (1.0f/512.0f) - mean*mean;
    float rs   = rsqrtf(var + 1e-5f);
    const float4* gr = (const float4*)g; const float4* br = (const float4*)bb;
    float4 g0 = gr[lane], g1 = gr[lane+64], b0 = br[lane], b1 = br[lane+64];
    ushort4 o0, o1;
    o0.x = f2bf((v0.x-mean)*rs*g0.x + b0.x);
    o0.y = f2bf((v0.y-mean)*rs*g0.y + b0.y);
    o0.z = f2bf((v0.z-mean)*rs*g0.z + b0.z);
    o0.w = f2bf((v0.w-mean)*rs*g0.w + b0.w);
    o1.x = f2bf((v1.x-mean)*rs*g1.x + b1.x);
    o1.y = f2bf((v1.y-mean)*rs*g1.y + b1.y);
    o1.z = f2bf((v1.z-mean)*rs*g1.z + b1.z);
    o1.w = f2bf((v1.w-mean)*rs*g1.w + b1.w);
    ushort4* orow = (ushort4*)(o + (long)row * 512);
    orow[lane] = o0; orow[lane + 64] = o1;
}

// ---------------- MFMA GEMM: XCD-swizzled + register-prefetch pipeline ------
// tile 128x128, BK=32, 4 waves (32 rows x 128 cols each), 16x16x32 MFMA.
// 1D grid of 72*nT blocks: xcd = id&7 owns a contiguous band of 9 m-tiles.
// K-loop = R1-proven register-prefetch shape (replay-safe): next tile's
// global loads issue into VGPRs before the MFMA phase; ds_write at top of
// next iteration. NOTE (R4): gl2lds double-buffering raced under graph
// replay. NOTE (R2-this-session): BK=64 reg-prefetch spilled to scratch
// (WRITE_SIZE 31->503 MB) — do not widen the prefetch state.
// LDS rows padded to LDK=40 elems (80 B = 20 banks): rows at a fixed
// quad-offset spread over all 8 bank-groups (r*20 mod 32 cycles 8 values)
// -> 2-way aliasing = free. Unpadded 64 B stride was an 8-way conflict
// (measured 4.99M SQ_LDS_BANK_CONFLICT cycles/dispatch).
// MODE 0: bias, bf16 out   MODE 1: bias + fp32 residual, fp32 out
// MODE 2: GLU pair -> bf16 gelu(u1)*u2, out (M,1920)
// MODE 3: policy masked store -> fp32 (B,4608)
template<int MODE>
__global__ __launch_bounds__(256) void gemm128(
    const unsigned short* __restrict__ A, const unsigned short* __restrict__ Bt,
    const float* __restrict__ bias, const float* __restrict__ res,
    void* __restrict__ out, int K, int ldo, int nT)
{
    __shared__ __attribute__((aligned(16))) unsigned short As[128*LDK];
    __shared__ __attribute__((aligned(16))) unsigned short Bs[128*LDK];
    int id = blockIdx.x;
    int xcd = id & 7, jj = id >> 3;
    int bn  = jj % nT;
    int mt  = xcd * MBAND + jj / nT;
    if (mt >= MTILES) return;
    int m0 = mt * 128;
    int tid = threadIdx.x;
    int lane = tid & 63, w = tid >> 6;
    int quad = lane >> 4, col = lane & 15;

    int srow = tid >> 2;          // 0..63
    int sc8  = (tid & 3) * 8;     // k element offset (8 bf16 = 16B)

    int br0, br1;
    if (MODE == 2) {
        br0 = bn*64 + srow;                 // u1 rows
        br1 = 1920 + bn*64 + srow;          // u2 rows
    } else {
        br0 = bn*128 + srow;
        br1 = bn*128 + srow + 64;
    }
    const unsigned short* Arow0 = A + (long)(m0 + srow) * K + sc8;
    const unsigned short* Arow1 = A + (long)(m0 + srow + 64) * K + sc8;
    const unsigned short* Brow0 = Bt + (long)br0 * K + sc8;
    const unsigned short* Brow1 = Bt + (long)br1 * K + sc8;

    f32x4 acc[2][8] = {};

    int4 ca0 = *(const int4*)(Arow0);
    int4 ca1 = *(const int4*)(Arow1);
    int4 cb0 = *(const int4*)(Brow0);
    int4 cb1 = *(const int4*)(Brow1);

    for (int k0 = 0; k0 < K; k0 += 32) {
        __syncthreads();   // prior iteration's frag reads done
        *(int4*)(&As[srow*LDK + sc8])        = ca0;
        *(int4*)(&As[(srow+64)*LDK + sc8])   = ca1;
        *(int4*)(&Bs[srow*LDK + sc8])        = cb0;
        *(int4*)(&Bs[(srow+64)*LDK + sc8])   = cb1;
        __syncthreads();
        int kn = k0 + 32;
        if (kn < K) {   // prefetch next tile into VGPRs while computing
            ca0 = *(const int4*)(Arow0 + kn);
            ca1 = *(const int4*)(Arow1 + kn);
            cb0 = *(const int4*)(Brow0 + kn);
            cb1 = *(const int4*)(Brow1 + kn);
        }
        bf16x8 af[2], bfr[8];
#pragma unroll
        for (int i = 0; i < 2; i++)
            af[i] = *(const bf16x8*)(&As[(w*32 + i*16 + col)*LDK + quad*8]);
#pragma unroll
        for (int t = 0; t < 8; t++)
            bfr[t] = *(const bf16x8*)(&Bs[(t*16 + col)*LDK + quad*8]);
#pragma unroll
        for (int i = 0; i < 2; i++)
#pragma unroll
            for (int t = 0; t < 8; t++)
                acc[i][t] = __builtin_amdgcn_mfma_f32_16x16x32_bf16(af[i], bfr[t], acc[i][t], 0, 0, 0);
    }

    // ---- epilogue ----  C/D layout: col = lane&15, row = quad*4 + reg
    if (MODE == 2) {
        unsigned short* O = (unsigned short*)out;
        int gn0 = bn * 64;
#pragma unroll
        for (int i = 0; i < 2; i++)
#pragma unroll
        for (int t = 0; t < 4; t++) {
            int c = t*16 + col;
            float b1v = bias[gn0 + c];
            float b2v = bias[1920 + gn0 + c];
#pragma unroll
            for (int r = 0; r < 4; r++) {
                int m = m0 + w*32 + i*16 + quad*4 + r;
                float u1 = acc[i][t][r]   + b1v;
                float u2 = acc[i][t+4][r] + b2v;
                O[(long)m * DFFH + gn0 + c] = f2bf(gelu_exact(u1) * u2);
            }
        }
        return;
    }
    int n0 = bn * 128;
#pragma unroll
    for (int i = 0; i < 2; i++)
#pragma unroll
    for (int t = 0; t < 8; t++) {
        int cg = n0 + t*16 + col;
        float bv = (MODE == 3) ? (cg < 72 ? bias[cg] : 0.0f) : bias[cg];
#pragma unroll
        for (int r = 0; r < 4; r++) {
            int m = m0 + w*32 + i*16 + quad*4 + r;
            float v = acc[i][t][r] + bv;
            if (MODE == 0) {
                ((unsigned short*)out)[(long)m * ldo + cg] = f2bf(v);
            } else if (MODE == 1) {
                ((float*)out)[(long)m * ldo + cg] = res[(long)m * ldo + cg] + v;
            } else { // MODE 3 policy
                if (cg < 72) {
                    int b2 = m / 65, s = m - b2 * 65;
                    if (s > 0)
                        ((float*)out)[(long)b2 * 4608 + (s - 1) * 72 + cg] = v;
                }
            }
        }
    }
}

// ---------------- MFMA attention: one block per (head, batch) ----------------
__global__ __launch_bounds__(256) void attn_mfma_kernel(
    const unsigned short* __restrict__ qkv,   // (M,1536) bf16: q|k|v
    const float* __restrict__ rel_bias,       // (13,15,15,8)
    unsigned short* __restrict__ ctx,         // (M,512) bf16
    int layer)
{
    constexpr int QS = 72;
    constexpr int VS = 104;
    constexpr int SS = 68;
    constexpr int PS = 104;
    __shared__ __attribute__((aligned(16))) unsigned short Qs[80*QS];
    __shared__ __attribute__((aligned(16))) unsigned short Ks[80*QS];
    __shared__ __attribute__((aligned(16))) unsigned short Vt[64*VS];
    __shared__ __attribute__((aligned(16))) float Sf[65*SS];
    __shared__ __attribute__((aligned(16))) unsigned short Pb[80*PS];
    __shared__ float bias_s[225];

    int h = blockIdx.x, b = blockIdx.y, t = threadIdx.x;
    int lane = t & 63, w = t >> 6;
    int quad = lane >> 4, col = lane & 15;

    for (int i = t; i < 225; i += 256)
        bias_s[i] = rel_bias[((long)layer*225 + i)*8 + h];

    for (int i = t; i < 65*8; i += 256) {
        int s = i >> 3, c8 = (i & 7) * 8;
        const unsigned short* row = qkv + ((long)(b*65+s))*1536 + h*64 + c8;
        int4 qv = *(const int4*)(row);
        int4 kv = *(const int4*)(row + 512);
        int4 vv = *(const int4*)(row + 1024);
        unsigned short qsc[8];
        const unsigned short* qp = (const unsigned short*)&qv;
#pragma unroll
        for (int j = 0; j < 8; j++) qsc[j] = f2bf(bf2f(qp[j]) * 0.125f);
        *(int4*)&Qs[s*QS + c8] = *(const int4*)qsc;
        *(int4*)&Ks[s*QS + c8] = kv;
        const unsigned short* vp = (const unsigned short*)&vv;
#pragma unroll
        for (int j = 0; j < 8; j++) Vt[(c8+j)*VS + s] = vp[j];
    }
    for (int i = t; i < 64*31; i += 256) {
        int d = i / 31, s = 65 + i % 31;
        Vt[d*VS + s] = 0;
    }
    __syncthreads();

    for (int tt = w; tt < 25; tt += 4) {
        int mi = tt / 5, nj = tt % 5;
        f32x4 acc = {};
        bf16x8 a0 = *(const bf16x8*)&Qs[(mi*16+col)*QS + quad*8];
        bf16x8 b0 = *(const bf16x8*)&Ks[(nj*16+col)*QS + quad*8];
        acc = __builtin_amdgcn_mfma_f32_16x16x32_bf16(a0, b0, acc, 0, 0, 0);
        bf16x8 a1 = *(const bf16x8*)&Qs[(mi*16+col)*QS + 32 + quad*8];
        bf16x8 b1 = *(const bf16x8*)&Ks[(nj*16+col)*QS + 32 + quad*8];
        acc = __builtin_amdgcn_mfma_f32_16x16x32_bf16(a1, b1, acc, 0, 0, 0);
#pragma unroll
        for (int r = 0; r < 4; r++) {
            int qi = mi*16 + quad*4 + r, kj = nj*16 + col;
            if (qi < 65 && kj < 65) {
                float v = acc[r];
                if (qi >= 1 && kj >= 1) {
                    int i2 = qi - 1, j2 = kj - 1;
                    int dr = (i2 >> 3) - (j2 >> 3) + 7;
                    int df = (i2 & 7) - (j2 & 7) + 7;
                    v += bias_s[dr*15 + df];
                }
                Sf[qi*SS + kj] = v;
            }
        }
    }
    __syncthreads();

    for (int r = w; r < 65; r += 4) {
        float x0 = Sf[r*SS + lane];
        float x1 = (lane == 0) ? Sf[r*SS + 64] : -1e30f;
        float mx = fmaxf(x0, x1);
        for (int off = 32; off; off >>= 1) mx = fmaxf(mx, __shfl_xor(mx, off));
        float e0 = __expf(x0 - mx);
        float e1 = (lane == 0) ? __expf(x1 - mx) : 0.0f;
        float sm = e0 + e1;
        for (int off = 32; off; off >>= 1) sm += __shfl_xor(sm, off);
        float inv = 1.0f / sm;
        Pb[r*PS + lane] = f2bf(e0 * inv);
        if (lane == 0)  Pb[r*PS + 64] = f2bf(e1 * inv);
        if (lane >= 1 && lane <= 31) Pb[r*PS + 64 + lane] = 0;
    }
    __syncthreads();

    for (int tt = w; tt < 20; tt += 4) {
        int mi = tt >> 2, dj = tt & 3;
        f32x4 acc = {};
#pragma unroll
        for (int ks = 0; ks < 3; ks++) {
            bf16x8 a  = *(const bf16x8*)&Pb[(mi*16+col)*PS + ks*32 + quad*8];
            bf16x8 bb = *(const bf16x8*)&Vt[(dj*16+col)*VS + ks*32 + quad*8];
            acc = __builtin_amdgcn_mfma_f32_16x16x32_bf16(a, bb, acc, 0, 0, 0);
        }
#pragma unroll
        for (int r = 0; r < 4; r++) {
            int qi = mi*16 + quad*4 + r;
            if (qi < 65)
                ctx[((long)(b*65+qi))*512 + h*64 + dj*16 + col] = f2bf(acc[r]);
        }
    }
}

// ---------------- value head ----------------
__global__ __launch_bounds__(256) void value_head_kernel(
    const unsigned short* __restrict__ hn,
    const float* __restrict__ vw1, const float* __restrict__ vb1,
    const float* __restrict__ vw2, const float* __restrict__ vb2,
    const float* __restrict__ vw3, const float* __restrict__ vb3,
    float* __restrict__ outv)
{
    int b = blockIdx.x, t = threadIdx.x;
    __shared__ float cls[512], v1[256], v2[128];
    for (int d = t; d < 512; d += 256) cls[d] = bf2f(hn[(long)b * SEQ * 512 + d]);
    __syncthreads();
    {
        float a = vb1[t];
        for (int c = 0; c < 512; c++) a += cls[c] * vw1[c*256 + t];
        v1[t] = gelu_exact(a);
    }
    __syncthreads();
    if (t < 128) {
        float a = vb2[t];
        for (int c = 0; c < 256; c++) a += v1[c] * vw2[c*128 + t];
        v2[t] = gelu_exact(a);
    }
    __syncthreads();
    if (t < 3) {
        float a = vb3[t];
        for (int c = 0; c < 128; c++) a += v2[c] * vw3[c*3 + t];
        outv[b*3 + t] = a;
    }
}

// ---------------- host orchestration ----------------
extern "C" void kernel_launch(void* const* d_in, const int* in_sizes, int n_in,
                              void* d_out, int out_size, void* d_ws, size_t ws_size,
                              hipStream_t stream)
{
    (void)in_sizes; (void)n_in; (void)out_size; (void)ws_size;
    const float* x        = (const float*)d_in[0];
    const float* conv_w   = (const float*)d_in[1];
    const float* conv_b   = (const float*)d_in[2];
    const float* cls_tok  = (const float*)d_in[3];
    const float* abs_pos  = (const float*)d_in[4];
    const float* file_emb = (const float*)d_in[5];
    const float* rank_emb = (const float*)d_in[6];
    const float* diag_emb = (const float*)d_in[7];
    const float* adiag    = (const float*)d_in[8];
    const float* ln1_g    = (const float*)d_in[9];
    const float* ln1_b    = (const float*)d_in[10];
    const float* wq       = (const float*)d_in[11];
    const float* bq       = (const float*)d_in[12];
    const float* wk       = (const float*)d_in[13];
    const float* bk       = (const float*)d_in[14];
    const float* wv       = (const float*)d_in[15];
    const float* bv       = (const float*)d_in[16];
    const float* wo       = (const float*)d_in[17];
    const float* bo       = (const float*)d_in[18];
    const float* rel_bias = (const float*)d_in[19];
    const float* ln2_g    = (const float*)d_in[20];
    const float* ln2_b    = (const float*)d_in[21];
    const float* w_ff1    = (const float*)d_in[22];
    const float* b_ff1    = (const float*)d_in[23];
    const float* w_ff2    = (const float*)d_in[24];
    const float* b_ff2    = (const float*)d_in[25];
    const float* out_g    = (const float*)d_in[26];
    const float* out_b    = (const float*)d_in[27];
    const float* vw1      = (const float*)d_in[28];
    const float* vb1      = (const float*)d_in[29];
    const float* vw2      = (const float*)d_in[30];
    const float* vb2      = (const float*)d_in[31];
    const float* vw3      = (const float*)d_in[32];
    const float* vb3      = (const float*)d_in[33];
    const float* pw       = (const float*)d_in[34];
    const float* pb       = (const float*)d_in[35];

    char* p = (char*)d_ws;
    auto alloc = [&](size_t bytes) { void* r = (void*)p; p += (bytes + 255) & ~(size_t)255; return r; };
    unsigned short* qkvT = (unsigned short*)alloc((size_t)NLAYER*1536*512*2);
    unsigned short* woT  = (unsigned short*)alloc((size_t)NLAYER*512*512*2);
    unsigned short* w1T  = (unsigned short*)alloc((size_t)NLAYER*3840*512*2);
    unsigned short* w2T  = (unsigned short*)alloc((size_t)NLAYER*512*1920*2);
    unsigned short* pwT  = (unsigned short*)alloc((size_t)128*512*2);
    float*          bqkv = (float*)alloc((size_t)NLAYER*1536*4);
    float*          h    = (float*)alloc((size_t)MROWS*512*4);
    unsigned short* nbf  = (unsigned short*)alloc((size_t)MROWS*512*2);
    unsigned short* qkvb = (unsigned short*)alloc((size_t)MROWS*1536*2);
    unsigned short* ctxb = (unsigned short*)alloc((size_t)MROWS*512*2);
    unsigned short* gbuf = (unsigned short*)alloc((size_t)MROWS*1920*2);

    dim3 tb(32, 8);
    transpose_f32_bf16<<<dim3(16,16,NLAYER), tb, 0, stream>>>(wq, qkvT, 512, 512, 512, 512L*512, 1536L*512, 0);
    transpose_f32_bf16<<<dim3(16,16,NLAYER), tb, 0, stream>>>(wk, qkvT, 512, 512, 512, 512L*512, 1536L*512, 512);
    transpose_f32_bf16<<<dim3(16,16,NLAYER), tb, 0, stream>>>(wv, qkvT, 512, 512, 512, 512L*512, 1536L*512, 1024);
    transpose_f32_bf16<<<dim3(16,16,NLAYER), tb, 0, stream>>>(wo, woT, 512, 512, 512, 512L*512, 512L*512, 0);
    transpose_f32_bf16<<<dim3(120,16,NLAYER), tb, 0, stream>>>(w_ff1, w1T, 512, 3840, 3840, 512L*3840, 3840L*512, 0);
    transpose_f32_bf16<<<dim3(16,60,NLAYER), tb, 0, stream>>>(w_ff2, w2T, 1920, 512, 512, 1920L*512, 512L*1920, 0);
    transpose_f32_bf16<<<dim3(4,16,1), tb, 0, stream>>>(pw, pwT, 512, 72, 128, 0, 0, 0);
    stack_bias_kernel<<<(NLAYER*1536 + 255)/256, 256, 0, stream>>>(bq, bk, bv, bqkv);

    embed_kernel<<<dim3(9, BATCH), 256, 0, stream>>>(x, conv_w, conv_b, cls_tok, abs_pos,
                                                     file_emb, rank_emb, diag_emb, adiag, h);

    for (int l = 0; l < NLAYER; l++) {
        ln_kernel<<<MROWS/4, 256, 0, stream>>>(h, ln1_g + l*512, ln1_b + l*512, nbf);
        gemm128<0><<<72*12, 256, 0, stream>>>(nbf, qkvT + (size_t)l*1536*512,
                                              bqkv + l*1536, nullptr, qkvb, 512, 1536, 12);
        attn_mfma_kernel<<<dim3(NHEAD, BATCH), 256, 0, stream>>>(qkvb, rel_bias, ctxb, l);
        gemm128<1><<<72*4, 256, 0, stream>>>(ctxb, woT + (size_t)l*512*512,
                                             bo + l*512, h, h, 512, 512, 4);
        ln_kernel<<<MROWS/4, 256, 0, stream>>>(h, ln2_g + l*512, ln2_b + l*512, nbf);
        gemm128<2><<<72*30, 256, 0, stream>>>(nbf, w1T + (size_t)l*3840*512,
                                              b_ff1 + l*3840, nullptr, gbuf, 512, 0, 30);
        gemm128<1><<<72*4, 256, 0, stream>>>(gbuf, w2T + (size_t)l*512*1920,
                                             b_ff2 + l*512, h, h, 1920, 512, 4);
    }

    ln_kernel<<<MROWS/4, 256, 0, stream>>>(h, out_g, out_b, nbf);
    gemm128<3><<<72*1, 256, 0, stream>>>(nbf, pwT, pb, nullptr, (float*)d_out, 512, 0, 1);
    value_head_kernel<<<BATCH, 256, 0, stream>>>(nbf, vw1, vb1, vw2, vb2, vw3, vb3,
                                                 (float*)d_out + (size_t)BATCH*4608);
}